// Round 11
// baseline (106.490 us; speedup 1.0000x reference)
//
#include <hip/hip_runtime.h>
#include <hip/hip_bf16.h>
#include <math.h>

#define Bb 64
#define Ss 30
#define Cc 62
#define Ll 169
#define CL (Cc*Ll)          // 10478
#define GRU 64
#define HTAPS 108           // 64+32+14-2
#define KSPLIT 32
#define NTILES 164          // 164*64 = 10496 >= 10478
#define HBS 10496           // padded K extent (zero rows 10478..10495)

typedef __attribute__((ext_vector_type(8))) short short8;
typedef __attribute__((ext_vector_type(4))) float f32x4;

__device__ __forceinline__ unsigned short f2bf(float f)
{
    union { float f; unsigned int u; } v; v.f = f;
    unsigned int u = v.u + 0x7fffu + ((v.u >> 16) & 1u);   // RNE
    return (unsigned short)(u >> 16);
}

// NOTE: the reference's iCOH adjacency is mathematically zero:
// sum_k f_i[k]*conj(f_j[k]) = L * sum_n x_i[n] x_j[n]  (Parseval, real x)
// => Im part == 0 => num == 0 => adj == 0 (diagonal masked anyway).
// The SE / max_seg / FFT branch contributes nothing and is elided.

// ---------------- K_prep: blocks 0..61 -> effective filter row c, write HBt;
//                  block 62 -> bias constant C + zero-pad HBt rows ----------------
// HBt[j][kg] (bf16): kg = c*169 + l; value = Heff[c][l-j] if 0<=l-j<108 else 0.
__global__ __launch_bounds__(256) void k_prep(
    const float* __restrict__ dwk1, const float* __restrict__ dwb1,
    const float* __restrict__ pwk1, const float* __restrict__ pwb1,
    const float* __restrict__ dwk2, const float* __restrict__ dwb2,
    const float* __restrict__ pwk2, const float* __restrict__ pwb2,
    const float* __restrict__ dwk3, const float* __restrict__ dwb3,
    const float* __restrict__ pwk3, const float* __restrict__ pwb3,
    float* __restrict__ Ccst, unsigned short* __restrict__ HBt)
{
    const int c = blockIdx.x, t = threadIdx.x;
    if (c == Cc) {
        // zero-pad rows kg in [10478, 10496)
        for (int u = t; u < 64*(HBS - CL); u += 256) {
            int j = u / (HBS - CL), l = u % (HBS - CL);
            HBt[(size_t)j*HBS + CL + l] = 0;
        }
        // bias constant C
        __shared__ float s0[Cc], s1[Cc], s2[Cc];
        if (t < Cc) s0[t] = dwb1[t];
        __syncthreads();
        if (t < Cc) {
            float acc = pwb1[t];
            for (int cc2 = 0; cc2 < Cc; ++cc2) acc += pwk1[t*Cc + cc2] * s0[cc2];
            float sk = 0.f;
            for (int a = 0; a < 32; ++a) sk += dwk2[t*32 + a];
            s1[t] = acc * sk + dwb2[t];
        }
        __syncthreads();
        if (t < Cc) {
            float acc = pwb2[t];
            for (int e = 0; e < Cc; ++e) acc += pwk2[t*Cc + e] * s1[e];
            float sk = 0.f;
            for (int tt = 0; tt < 14; ++tt) sk += dwk3[t*14 + tt];
            s2[t] = acc * sk + dwb3[t];
        }
        __syncthreads();
        if (t < 64) {
            float v = (t < Cc) ? pwk3[61*Cc + t] * s2[t] : 0.f;
            for (int off = 32; off; off >>= 1) v += __shfl_down(v, off);
            if (t == 0) Ccst[0] = v + pwb3[61];
        }
        return;
    }
    // ---- per-c effective filter ----
    __shared__ float q[Cc];
    __shared__ float F[Cc*14];     // F[e][t] = sum_f q[f]*pwk2[f,e]*dwk3[f,t]
    __shared__ float G[Cc*45];     // G[e] = F[e] conv dwk2[e]
    __shared__ float H1[45], hc[HTAPS];
    if (t < Cc) q[t] = pwk3[61*Cc + t];
    __syncthreads();
    for (int u = t; u < Cc*14; u += 256) {
        int e = u / 14, tt = u % 14;
        float acc = 0.f;
        for (int f = 0; f < Cc; ++f) acc += q[f] * pwk2[f*Cc + e] * dwk3[f*14 + tt];
        F[u] = acc;
    }
    __syncthreads();
    for (int u = t; u < Cc*45; u += 256) {
        int e = u / 45, s = u % 45;
        float acc = 0.f;
        int t0 = s - 31; if (t0 < 0) t0 = 0;
        int t1 = s; if (t1 > 13) t1 = 13;
        for (int tt = t0; tt <= t1; ++tt) acc += F[e*14 + tt] * dwk2[e*32 + (s - tt)];
        G[u] = acc;
    }
    __syncthreads();
    if (t < 45) {
        float acc = 0.f;
        for (int e = 0; e < Cc; ++e) acc += pwk1[e*Cc + c] * G[e*45 + t];
        H1[t] = acc;
    }
    __syncthreads();
    if (t < HTAPS) {
        float acc = 0.f;
        int s0 = t - 63; if (s0 < 0) s0 = 0;
        int s1 = t; if (s1 > 44) s1 = 44;
        for (int s = s0; s <= s1; ++s) acc += H1[s] * dwk1[c*64 + (t - s)];
        hc[t] = acc;
    }
    __syncthreads();
    for (int u = t; u < 64*Ll; u += 256) {
        int j = u / Ll, l = u - j*Ll;
        int a = l - j;
        unsigned short v = 0;
        if (a >= 0 && a < HTAPS) v = f2bf(hc[a]);
        HBt[(size_t)j*HBS + c*Ll + l] = v;
    }
}

// ---------------- K_gemm: MFMA  P[ks][1920][62] = X*H (bf16) ----------------
__global__ __launch_bounds__(256) void k_gemm(const float* __restrict__ x,
                                              const unsigned short* __restrict__ HBt,
                                              float* __restrict__ P)
{
    __shared__ __align__(16) unsigned short Xs[64*64];
    __shared__ __align__(16) unsigned short Hs[64*64];
    const int tid = threadIdx.x;
    const int mt = blockIdx.x % 30;
    const int ks = blockIdx.x / 30;
    const int t0 = (NTILES * ks) / KSPLIT;
    const int t1 = (NTILES * (ks + 1)) / KSPLIT;
    const int m0g = mt * 64;
    const int w = tid >> 6, l = tid & 63;
    const int arow = w*16 + (l & 15);
    const int klane = (l >> 4) * 8;
    const int sr = tid >> 2, sq4 = (tid & 3) << 4;

    f32x4 acc[4];
#pragma unroll
    for (int ct = 0; ct < 4; ++ct) acc[ct] = (f32x4){0.f, 0.f, 0.f, 0.f};

    for (int kt = t0; kt < t1; ++kt) {
        const int kb = kt * 64;
        // ---- stage X tile (fp32 -> bf16, swizzled) ----
        {
            const float* xp = x + (size_t)(m0g + sr)*CL + kb + sq4;
            unsigned short tb[16];
            if (kb + 64 <= CL) {
#pragma unroll
                for (int t2 = 0; t2 < 8; ++t2) {
                    float2 v = *reinterpret_cast<const float2*>(xp + 2*t2);
                    tb[2*t2]   = f2bf(v.x);
                    tb[2*t2+1] = f2bf(v.y);
                }
            } else {
#pragma unroll
                for (int t = 0; t < 16; ++t) {
                    int col = kb + sq4 + t;
                    tb[t] = f2bf((col < CL) ? xp[t] : 0.f);
                }
            }
            int i0 = (sr*64 + sq4)     ^ ((sr & 7) << 3);
            int i1 = (sr*64 + sq4 + 8) ^ ((sr & 7) << 3);
            short8 p0, p1;
#pragma unroll
            for (int t = 0; t < 8; ++t) { p0[t] = (short)tb[t]; p1[t] = (short)tb[t+8]; }
            *reinterpret_cast<short8*>(&Xs[i0]) = p0;
            *reinterpret_cast<short8*>(&Xs[i1]) = p1;
        }
        // ---- stage H tile: pure short8 loads from HBt ----
        {
            const unsigned short* hp = HBt + (size_t)sr*HBS + kb + sq4;
            short8 p0 = *reinterpret_cast<const short8*>(hp);
            short8 p1 = *reinterpret_cast<const short8*>(hp + 8);
            int i0 = (sr*64 + sq4)     ^ ((sr & 7) << 3);
            int i1 = (sr*64 + sq4 + 8) ^ ((sr & 7) << 3);
            *reinterpret_cast<short8*>(&Hs[i0]) = p0;
            *reinterpret_cast<short8*>(&Hs[i1]) = p1;
        }
        __syncthreads();
#pragma unroll
        for (int ks2 = 0; ks2 < 2; ++ks2) {
            int kk0 = ks2*32 + klane;
            int ia = (arow*64 + kk0) ^ ((arow & 7) << 3);
            short8 af = *reinterpret_cast<const short8*>(&Xs[ia]);
#pragma unroll
            for (int ct = 0; ct < 4; ++ct) {
                int bcol = ct*16 + (l & 15);
                int ib = (bcol*64 + kk0) ^ ((bcol & 7) << 3);
                short8 bf = *reinterpret_cast<const short8*>(&Hs[ib]);
                acc[ct] = __builtin_amdgcn_mfma_f32_16x16x32_bf16(af, bf, acc[ct], 0, 0, 0);
            }
        }
        __syncthreads();
    }
#pragma unroll
    for (int ct = 0; ct < 4; ++ct) {
        int col = ct*16 + (l & 15);
        if (col < Cc) {
#pragma unroll
            for (int i = 0; i < 4; ++i) {
                int row = m0g + w*16 + (l >> 4)*4 + i;
                P[(size_t)(ks*1920 + row)*Cc + col] = acc[ct][i];
            }
        }
    }
}

// ---------------- K_g: adj_t = sigmoid(C + sum_ks P) , v, g, pre-gates ----------------
__global__ __launch_bounds__(256) void k_g(const float* __restrict__ x, const float* __restrict__ P,
    const float* __restrict__ Ccst,
    const float* __restrict__ gcn_w, const float* __restrict__ gcn_b,
    const float* __restrict__ w_r, const float* __restrict__ w_u, const float* __restrict__ w_c,
    float* __restrict__ preR, float* __restrict__ preU, float* __restrict__ preC)
{
    __shared__ float adjt[Cc];
    __shared__ float v[Ll];
    __shared__ float g[GRU];
    int bt = blockIdx.x, t = bt >> 6, b = bt & 63;
    int m = b * Ss + t;
    int tid = threadIdx.x;
    if (tid < Cc) {
        float sv = Ccst[0];
#pragma unroll
        for (int ks = 0; ks < KSPLIT; ++ks) sv += P[((size_t)ks*1920 + m)*Cc + tid];
        adjt[tid] = 1.f / (1.f + expf(-sv));
    }
    __syncthreads();
    if (tid < Ll) {
        const float* xp = x + (size_t)m*CL + tid;
        float acc = 0.f;
        for (int j = 0; j < Cc; ++j) acc += adjt[j] * xp[j*Ll];
        v[tid] = acc;
    }
    __syncthreads();
    if (tid < GRU) {
        float acc = gcn_b[tid];
        for (int l = 0; l < Ll; ++l) acc += v[l] * gcn_w[l*GRU + tid];
        g[tid] = acc;
    }
    __syncthreads();
    if (tid < GRU) {
        float ar = 0.f, au = 0.f, ac = 0.f;
        for (int i = 0; i < GRU; ++i) {
            float gi = g[i];
            ar += gi * w_r[i*GRU + tid];
            au += gi * w_u[i*GRU + tid];
            ac += gi * w_c[i*GRU + tid];
        }
        preR[(size_t)bt*GRU + tid] = ar;
        preU[(size_t)bt*GRU + tid] = au;
        preC[(size_t)bt*GRU + tid] = ac;
    }
}

// ---------------- K_gru: 4-wave cooperative scan ----------------
__global__ __launch_bounds__(256) void k_gru(const float* __restrict__ preR, const float* __restrict__ preU,
    const float* __restrict__ preC,
    const float* __restrict__ w_r, const float* __restrict__ wb_r,
    const float* __restrict__ w_u, const float* __restrict__ wb_u,
    const float* __restrict__ w_c, const float* __restrict__ wb_c,
    const float* __restrict__ b_r, const float* __restrict__ b_u, const float* __restrict__ b_c,
    float* __restrict__ out)
{
    __shared__ float h[GRU], rh[GRU];
    __shared__ float part[3][4][GRU];
    __shared__ float preS[Ss][3][GRU];
    const int b = blockIdx.x;
    const int t = threadIdx.x, o = t & 63, q = t >> 6;

    float wr[16], wu[16], wc[16];
#pragma unroll
    for (int i = 0; i < 16; ++i) {
        wr[i] = w_r[(GRU + q*16 + i)*GRU + o];
        wu[i] = w_u[(GRU + q*16 + i)*GRU + o];
        wc[i] = w_c[(GRU + q*16 + i)*GRU + o];
    }
    for (int u = t; u < Ss*GRU; u += 256) {
        int s = u >> 6, oo = u & 63;
        size_t base = (size_t)(s*Bb + b)*GRU + oo;
        preS[s][0][oo] = preR[base];
        preS[s][1][oo] = preU[base];
        preS[s][2][oo] = preC[base];
    }
    const float cr = wb_r[o] + b_r[o];
    const float cu = wb_u[o] + b_u[o];
    const float cc = wb_c[o] + b_c[o];
    if (t < GRU) h[t] = 0.f;
    float ug = 0.f;
    __syncthreads();

    for (int s = 0; s < Ss; ++s) {
        float ar = 0.f, au = 0.f;
#pragma unroll
        for (int i = 0; i < 16; ++i) {
            float hi = h[q*16 + i];
            ar += hi * wr[i];
            au += hi * wu[i];
        }
        part[0][q][o] = ar;
        part[1][q][o] = au;
        __syncthreads();
        if (q == 0) {
            float arf = preS[s][0][o] + cr + part[0][0][o] + part[0][1][o] + part[0][2][o] + part[0][3][o];
            float auf = preS[s][1][o] + cu + part[1][0][o] + part[1][1][o] + part[1][2][o] + part[1][3][o];
            float r = 1.f / (1.f + expf(-arf));
            ug = 1.f / (1.f + expf(-auf));
            rh[o] = r * h[o];
        }
        __syncthreads();
        float ac = 0.f;
#pragma unroll
        for (int i = 0; i < 16; ++i) ac += rh[q*16 + i] * wc[i];
        part[2][q][o] = ac;
        __syncthreads();
        if (q == 0) {
            float acf = preS[s][2][o] + cc + part[2][0][o] + part[2][1][o] + part[2][2][o] + part[2][3][o];
            float ct = tanhf(acf);
            float hn = ug * h[o] + (1.f - ug) * ct;
            h[o] = hn;
            if (s == Ss - 1) out[b*GRU + o] = hn;
        }
        __syncthreads();
    }
}

// ---------------- launcher ----------------
extern "C" void kernel_launch(void* const* d_in, const int* in_sizes, int n_in,
                              void* d_out, int out_size, void* d_ws, size_t ws_size,
                              hipStream_t stream)
{
    const float* x     = (const float*)d_in[0];
    const float* dwk1  = (const float*)d_in[3];
    const float* dwb1  = (const float*)d_in[4];
    const float* pwk1  = (const float*)d_in[5];
    const float* pwb1  = (const float*)d_in[6];
    const float* dwk2  = (const float*)d_in[7];
    const float* dwb2  = (const float*)d_in[8];
    const float* pwk2  = (const float*)d_in[9];
    const float* pwb2  = (const float*)d_in[10];
    const float* dwk3  = (const float*)d_in[11];
    const float* dwb3  = (const float*)d_in[12];
    const float* pwk3  = (const float*)d_in[13];
    const float* pwb3  = (const float*)d_in[14];
    const float* gcn_w = (const float*)d_in[15];
    const float* gcn_b = (const float*)d_in[16];
    const float* w_r   = (const float*)d_in[17];
    const float* wb_r  = (const float*)d_in[18];
    const float* w_u   = (const float*)d_in[19];
    const float* wb_u  = (const float*)d_in[20];
    const float* w_c   = (const float*)d_in[21];
    const float* wb_c  = (const float*)d_in[22];
    const float* b_r   = (const float*)d_in[23];
    const float* b_u   = (const float*)d_in[24];
    const float* b_c   = (const float*)d_in[25];
    float* out = (float*)d_out;

    // flat workspace (floats), ~17 MB
    float* ws   = (float*)d_ws;
    float* P    = ws;                    // 32 x 1920 x 62 = 3,809,280
    float* preR = P    + 3809280;        // 122880
    float* preU = preR + 122880;         // 122880
    float* preC = preU + 122880;         // 122880
    float* Ccst = preC + 122880;         // 8
    unsigned short* HBt = (unsigned short*)(Ccst + 8);   // 64*10496 = 671,744 ushorts

    k_prep<<<Cc + 1, 256, 0, stream>>>(dwk1, dwb1, pwk1, pwb1, dwk2, dwb2, pwk2, pwb2,
                                       dwk3, dwb3, pwk3, pwb3, Ccst, HBt);
    k_gemm<<<30*KSPLIT, 256, 0, stream>>>(x, HBt, P);
    k_g<<<Ss*Bb, 256, 0, stream>>>(x, P, Ccst, gcn_w, gcn_b, w_r, w_u, w_c, preR, preU, preC);
    k_gru<<<Bb, 256, 0, stream>>>(preR, preU, preC, w_r, wb_r, w_u, wb_u, w_c, wb_c,
                                  b_r, b_u, b_c, out);
}

// Round 12
// 87.375 us; speedup vs baseline: 1.2188x; 1.2188x over previous
//
#include <hip/hip_runtime.h>
#include <hip/hip_bf16.h>
#include <math.h>

#define Bb 64
#define Ss 30
#define Cc 62
#define Ll 169
#define CL (Cc*Ll)          // 10478
#define GRU 64
#define HTAPS 108           // 64+32+14-2
#define KSPLIT 16
#define NTILES 164          // 164*64 = 10496 >= 10478
#define HBS 10496           // padded K extent (zero cols 10478..10495)

typedef __attribute__((ext_vector_type(8))) short short8;
typedef __attribute__((ext_vector_type(4))) float f32x4;

__device__ __forceinline__ unsigned short f2bf(float f)
{
    union { float f; unsigned int u; } v; v.f = f;
    unsigned int u = v.u + 0x7fffu + ((v.u >> 16) & 1u);   // RNE
    return (unsigned short)(u >> 16);
}

// NOTE: the reference's iCOH adjacency is mathematically zero:
// sum_k f_i[k]*conj(f_j[k]) = L * sum_n x_i[n] x_j[n]  (Parseval, real x)
// => Im part == 0 => num == 0 => adj == 0 (diagonal masked anyway).
// The SE / max_seg / FFT branch contributes nothing and is elided.

// ---------------- K_misc: blk<62 -> G[e]; blk==62 -> bias constant C ----------------
__global__ __launch_bounds__(256) void k_misc(
    const float* __restrict__ pwk1, const float* __restrict__ pwb1, const float* __restrict__ dwb1,
    const float* __restrict__ dwk2, const float* __restrict__ dwb2,
    const float* __restrict__ pwk2, const float* __restrict__ pwb2,
    const float* __restrict__ dwk3, const float* __restrict__ dwb3,
    const float* __restrict__ pwk3, const float* __restrict__ pwb3,
    float* __restrict__ Gout, float* __restrict__ Ccst)
{
    __shared__ float s0[Cc], s1[Cc], s2[Cc], F[14], k2[32];
    const int blk = blockIdx.x, t = threadIdx.x;
    if (blk < Cc) {
        // F[t] = sum_f pwk3[61,f]*pwk2[f,e]*dwk3[f,t];  G[e] = F conv dwk2[e]
        const int e = blk;
        if (t < Cc) { s0[t] = pwk3[61*Cc + t]; s1[t] = pwk2[t*Cc + e]; }
        if (t < 32) k2[t] = dwk2[e*32 + t];
        __syncthreads();
        if (t < 14) {
            float acc = 0.f;
            for (int f = 0; f < Cc; ++f) acc += s0[f] * s1[f] * dwk3[f*14 + t];
            F[t] = acc;
        }
        __syncthreads();
        if (t < 45) {
            float acc = 0.f;
            int t0 = t - 31; if (t0 < 0) t0 = 0;
            int t1 = t; if (t1 > 13) t1 = 13;
            for (int tt = t0; tt <= t1; ++tt) acc += F[tt] * k2[t - tt];
            Gout[e*45 + t] = acc;
        }
    } else {
        // bias constant C
        if (t < Cc) s0[t] = dwb1[t];
        __syncthreads();
        if (t < Cc) {
            float acc = pwb1[t];
            for (int c = 0; c < Cc; ++c) acc += pwk1[t*Cc + c] * s0[c];
            float sk = 0.f;
            for (int a = 0; a < 32; ++a) sk += dwk2[t*32 + a];
            s1[t] = acc * sk + dwb2[t];
        }
        __syncthreads();
        if (t < Cc) {
            float acc = pwb2[t];
            for (int e = 0; e < Cc; ++e) acc += pwk2[t*Cc + e] * s1[e];
            float sk = 0.f;
            for (int tt = 0; tt < 14; ++tt) sk += dwk3[t*14 + tt];
            s2[t] = acc * sk + dwb3[t];
        }
        __syncthreads();
        if (t < 64) {
            float v = (t < Cc) ? pwk3[61*Cc + t] * s2[t] : 0.f;
            for (int off = 32; off; off >>= 1) v += __shfl_down(v, off);
            if (t == 0) Ccst[0] = v + pwb3[61];
        }
    }
}

// ---------------- K_h1h: blk<62 -> H1[c] -> hc -> HBt rows; blk==62 -> zero-pad ----------------
// HBt[j][kg] (bf16): kg = c*169 + l; value = hc[l-j] if 0<=l-j<108 else 0.
__global__ __launch_bounds__(256) void k_h1h(const float* __restrict__ pwk1, const float* __restrict__ dwk1,
                                             const float* __restrict__ Gin,
                                             unsigned short* __restrict__ HBt)
{
    const int c = blockIdx.x, t = threadIdx.x;
    if (c == Cc) {
        for (int u = t; u < 64*(HBS - CL); u += 256) {
            int j = u / (HBS - CL), l = u % (HBS - CL);
            HBt[(size_t)j*HBS + CL + l] = 0;
        }
        return;
    }
    __shared__ float p1c[Cc], H1[45], k1[64], hc[HTAPS];
    if (t < Cc) p1c[t] = pwk1[t*Cc + c];
    if (t >= 64 && t < 128) k1[t - 64] = dwk1[c*64 + (t - 64)];
    __syncthreads();
    if (t < 45) {
        float acc = 0.f;
        for (int e = 0; e < Cc; ++e) acc += p1c[e] * Gin[e*45 + t];
        H1[t] = acc;
    }
    __syncthreads();
    if (t < HTAPS) {
        float acc = 0.f;
        int s0 = t - 63; if (s0 < 0) s0 = 0;
        int s1 = t; if (s1 > 44) s1 = 44;
        for (int s = s0; s <= s1; ++s) acc += H1[s] * k1[t - s];
        hc[t] = acc;
    }
    __syncthreads();
    for (int u = t; u < 64*Ll; u += 256) {
        int j = u / Ll, l = u - j*Ll;
        int a = l - j;
        unsigned short v = 0;
        if (a >= 0 && a < HTAPS) v = f2bf(hc[a]);
        HBt[(size_t)j*HBS + c*Ll + l] = v;
    }
}

// ---------------- K_gemm: MFMA  P[ks][1920][62] = X*H (bf16) ----------------
__global__ __launch_bounds__(256) void k_gemm(const float* __restrict__ x,
                                              const unsigned short* __restrict__ HBt,
                                              float* __restrict__ P)
{
    __shared__ __align__(16) unsigned short Xs[64*64];
    __shared__ __align__(16) unsigned short Hs[64*64];
    const int tid = threadIdx.x;
    const int mt = blockIdx.x % 30;
    const int ks = blockIdx.x / 30;
    const int t0 = (NTILES * ks) / KSPLIT;
    const int t1 = (NTILES * (ks + 1)) / KSPLIT;
    const int m0g = mt * 64;
    const int w = tid >> 6, l = tid & 63;
    const int arow = w*16 + (l & 15);
    const int klane = (l >> 4) * 8;
    const int sr = tid >> 2, sq4 = (tid & 3) << 4;

    f32x4 acc[4];
#pragma unroll
    for (int ct = 0; ct < 4; ++ct) acc[ct] = (f32x4){0.f, 0.f, 0.f, 0.f};

    for (int kt = t0; kt < t1; ++kt) {
        const int kb = kt * 64;
        // ---- stage X tile (fp32 -> bf16, swizzled) ----
        {
            const float* xp = x + (size_t)(m0g + sr)*CL + kb + sq4;
            unsigned short tb[16];
            if (kb + 64 <= CL) {
#pragma unroll
                for (int t2 = 0; t2 < 8; ++t2) {
                    float2 v = *reinterpret_cast<const float2*>(xp + 2*t2);
                    tb[2*t2]   = f2bf(v.x);
                    tb[2*t2+1] = f2bf(v.y);
                }
            } else {
#pragma unroll
                for (int t = 0; t < 16; ++t) {
                    int col = kb + sq4 + t;
                    tb[t] = f2bf((col < CL) ? xp[t] : 0.f);
                }
            }
            int i0 = (sr*64 + sq4)     ^ ((sr & 7) << 3);
            int i1 = (sr*64 + sq4 + 8) ^ ((sr & 7) << 3);
            short8 p0, p1;
#pragma unroll
            for (int t = 0; t < 8; ++t) { p0[t] = (short)tb[t]; p1[t] = (short)tb[t+8]; }
            *reinterpret_cast<short8*>(&Xs[i0]) = p0;
            *reinterpret_cast<short8*>(&Xs[i1]) = p1;
        }
        // ---- stage H tile: pure short8 loads from HBt ----
        {
            const unsigned short* hp = HBt + (size_t)sr*HBS + kb + sq4;
            short8 p0 = *reinterpret_cast<const short8*>(hp);
            short8 p1 = *reinterpret_cast<const short8*>(hp + 8);
            int i0 = (sr*64 + sq4)     ^ ((sr & 7) << 3);
            int i1 = (sr*64 + sq4 + 8) ^ ((sr & 7) << 3);
            *reinterpret_cast<short8*>(&Hs[i0]) = p0;
            *reinterpret_cast<short8*>(&Hs[i1]) = p1;
        }
        __syncthreads();
#pragma unroll
        for (int ks2 = 0; ks2 < 2; ++ks2) {
            int kk0 = ks2*32 + klane;
            int ia = (arow*64 + kk0) ^ ((arow & 7) << 3);
            short8 af = *reinterpret_cast<const short8*>(&Xs[ia]);
#pragma unroll
            for (int ct = 0; ct < 4; ++ct) {
                int bcol = ct*16 + (l & 15);
                int ib = (bcol*64 + kk0) ^ ((bcol & 7) << 3);
                short8 bf = *reinterpret_cast<const short8*>(&Hs[ib]);
                acc[ct] = __builtin_amdgcn_mfma_f32_16x16x32_bf16(af, bf, acc[ct], 0, 0, 0);
            }
        }
        __syncthreads();
    }
#pragma unroll
    for (int ct = 0; ct < 4; ++ct) {
        int col = ct*16 + (l & 15);
        if (col < Cc) {
#pragma unroll
            for (int i = 0; i < 4; ++i) {
                int row = m0g + w*16 + (l >> 4)*4 + i;
                P[(size_t)(ks*1920 + row)*Cc + col] = acc[ct][i];
            }
        }
    }
}

// ---------------- K_g: adj_t = sigmoid(C + sum_ks P) , v, g, pre-gates ----------------
__global__ __launch_bounds__(256) void k_g(const float* __restrict__ x, const float* __restrict__ P,
    const float* __restrict__ Ccst,
    const float* __restrict__ gcn_w, const float* __restrict__ gcn_b,
    const float* __restrict__ w_r, const float* __restrict__ w_u, const float* __restrict__ w_c,
    float* __restrict__ preR, float* __restrict__ preU, float* __restrict__ preC)
{
    __shared__ float adjt[Cc];
    __shared__ float v[Ll];
    __shared__ float g[GRU];
    int bt = blockIdx.x, t = bt >> 6, b = bt & 63;
    int m = b * Ss + t;
    int tid = threadIdx.x;
    if (tid < Cc) {
        float sv = Ccst[0];
#pragma unroll
        for (int ks = 0; ks < KSPLIT; ++ks) sv += P[((size_t)ks*1920 + m)*Cc + tid];
        adjt[tid] = 1.f / (1.f + expf(-sv));
    }
    __syncthreads();
    if (tid < Ll) {
        const float* xp = x + (size_t)m*CL + tid;
        float acc = 0.f;
        for (int j = 0; j < Cc; ++j) acc += adjt[j] * xp[j*Ll];
        v[tid] = acc;
    }
    __syncthreads();
    if (tid < GRU) {
        float acc = gcn_b[tid];
        for (int l = 0; l < Ll; ++l) acc += v[l] * gcn_w[l*GRU + tid];
        g[tid] = acc;
    }
    __syncthreads();
    if (tid < GRU) {
        float ar = 0.f, au = 0.f, ac = 0.f;
        for (int i = 0; i < GRU; ++i) {
            float gi = g[i];
            ar += gi * w_r[i*GRU + tid];
            au += gi * w_u[i*GRU + tid];
            ac += gi * w_c[i*GRU + tid];
        }
        preR[(size_t)bt*GRU + tid] = ar;
        preU[(size_t)bt*GRU + tid] = au;
        preC[(size_t)bt*GRU + tid] = ac;
    }
}

// ---------------- K_gru: 4-wave cooperative scan ----------------
__global__ __launch_bounds__(256) void k_gru(const float* __restrict__ preR, const float* __restrict__ preU,
    const float* __restrict__ preC,
    const float* __restrict__ w_r, const float* __restrict__ wb_r,
    const float* __restrict__ w_u, const float* __restrict__ wb_u,
    const float* __restrict__ w_c, const float* __restrict__ wb_c,
    const float* __restrict__ b_r, const float* __restrict__ b_u, const float* __restrict__ b_c,
    float* __restrict__ out)
{
    __shared__ float h[GRU], rh[GRU];
    __shared__ float part[3][4][GRU];
    __shared__ float preS[Ss][3][GRU];
    const int b = blockIdx.x;
    const int t = threadIdx.x, o = t & 63, q = t >> 6;

    float wr[16], wu[16], wc[16];
#pragma unroll
    for (int i = 0; i < 16; ++i) {
        wr[i] = w_r[(GRU + q*16 + i)*GRU + o];
        wu[i] = w_u[(GRU + q*16 + i)*GRU + o];
        wc[i] = w_c[(GRU + q*16 + i)*GRU + o];
    }
    for (int u = t; u < Ss*GRU; u += 256) {
        int s = u >> 6, oo = u & 63;
        size_t base = (size_t)(s*Bb + b)*GRU + oo;
        preS[s][0][oo] = preR[base];
        preS[s][1][oo] = preU[base];
        preS[s][2][oo] = preC[base];
    }
    const float cr = wb_r[o] + b_r[o];
    const float cu = wb_u[o] + b_u[o];
    const float cc = wb_c[o] + b_c[o];
    if (t < GRU) h[t] = 0.f;
    float ug = 0.f;
    __syncthreads();

    for (int s = 0; s < Ss; ++s) {
        float ar = 0.f, au = 0.f;
#pragma unroll
        for (int i = 0; i < 16; ++i) {
            float hi = h[q*16 + i];
            ar += hi * wr[i];
            au += hi * wu[i];
        }
        part[0][q][o] = ar;
        part[1][q][o] = au;
        __syncthreads();
        if (q == 0) {
            float arf = preS[s][0][o] + cr + part[0][0][o] + part[0][1][o] + part[0][2][o] + part[0][3][o];
            float auf = preS[s][1][o] + cu + part[1][0][o] + part[1][1][o] + part[1][2][o] + part[1][3][o];
            float r = 1.f / (1.f + expf(-arf));
            ug = 1.f / (1.f + expf(-auf));
            rh[o] = r * h[o];
        }
        __syncthreads();
        float ac = 0.f;
#pragma unroll
        for (int i = 0; i < 16; ++i) ac += rh[q*16 + i] * wc[i];
        part[2][q][o] = ac;
        __syncthreads();
        if (q == 0) {
            float acf = preS[s][2][o] + cc + part[2][0][o] + part[2][1][o] + part[2][2][o] + part[2][3][o];
            float ct = tanhf(acf);
            float hn = ug * h[o] + (1.f - ug) * ct;
            h[o] = hn;
            if (s == Ss - 1) out[b*GRU + o] = hn;
        }
        __syncthreads();
    }
}

// ---------------- launcher ----------------
extern "C" void kernel_launch(void* const* d_in, const int* in_sizes, int n_in,
                              void* d_out, int out_size, void* d_ws, size_t ws_size,
                              hipStream_t stream)
{
    const float* x     = (const float*)d_in[0];
    const float* dwk1  = (const float*)d_in[3];
    const float* dwb1  = (const float*)d_in[4];
    const float* pwk1  = (const float*)d_in[5];
    const float* pwb1  = (const float*)d_in[6];
    const float* dwk2  = (const float*)d_in[7];
    const float* dwb2  = (const float*)d_in[8];
    const float* pwk2  = (const float*)d_in[9];
    const float* pwb2  = (const float*)d_in[10];
    const float* dwk3  = (const float*)d_in[11];
    const float* dwb3  = (const float*)d_in[12];
    const float* pwk3  = (const float*)d_in[13];
    const float* pwb3  = (const float*)d_in[14];
    const float* gcn_w = (const float*)d_in[15];
    const float* gcn_b = (const float*)d_in[16];
    const float* w_r   = (const float*)d_in[17];
    const float* wb_r  = (const float*)d_in[18];
    const float* w_u   = (const float*)d_in[19];
    const float* wb_u  = (const float*)d_in[20];
    const float* w_c   = (const float*)d_in[21];
    const float* wb_c  = (const float*)d_in[22];
    const float* b_r   = (const float*)d_in[23];
    const float* b_u   = (const float*)d_in[24];
    const float* b_c   = (const float*)d_in[25];
    float* out = (float*)d_out;

    // flat workspace (floats), ~10 MB
    float* ws   = (float*)d_ws;
    float* P    = ws;                    // 16 x 1920 x 62 = 1,904,640
    float* preR = P    + 1904640;        // 122880
    float* preU = preR + 122880;         // 122880
    float* preC = preU + 122880;         // 122880
    float* Ccst = preC + 122880;         // 8
    float* Gbuf = Ccst + 8;              // 2790
    unsigned short* HBt = (unsigned short*)(Gbuf + 2790);   // 64*10496 ushorts

    k_misc<<<Cc + 1, 256, 0, stream>>>(pwk1, pwb1, dwb1, dwk2, dwb2, pwk2, pwb2,
                                       dwk3, dwb3, pwk3, pwb3, Gbuf, Ccst);
    k_h1h<<<Cc + 1, 256, 0, stream>>>(pwk1, dwk1, Gbuf, HBt);
    k_gemm<<<30*KSPLIT, 256, 0, stream>>>(x, HBt, P);
    k_g<<<Ss*Bb, 256, 0, stream>>>(x, P, Ccst, gcn_w, gcn_b, w_r, w_u, w_c, preR, preU, preC);
    k_gru<<<Bb, 256, 0, stream>>>(preR, preU, preC, w_r, wb_r, w_u, wb_u, w_c, wb_c,
                                  b_r, b_u, b_c, out);
}